// Round 3
// baseline (1861.112 us; speedup 1.0000x reference)
//
#include <hip/hip_runtime.h>

#define FEAT   64
#define BSHIFT 8                 // 256 dst-nodes per bucket
#define BNODES 256
#define MAXB   512               // supports N <= 131072
#define CHUNK  4096              // edges per partition block

// ---------------- Pass 1: per-bucket edge counts ----------------
__global__ __launch_bounds__(256) void bucket_count_kernel(
    const int* __restrict__ dst, int* __restrict__ bcnt, int E)
{
    __shared__ int cnt[MAXB];
    for (int i = threadIdx.x; i < MAXB; i += 256) cnt[i] = 0;
    __syncthreads();
    int base = blockIdx.x * CHUNK;
    for (int i = threadIdx.x; i < CHUNK; i += 256) {
        int e = base + i;
        if (e < E) atomicAdd(&cnt[dst[e] >> BSHIFT], 1);
    }
    __syncthreads();
    for (int i = threadIdx.x; i < MAXB; i += 256)
        if (cnt[i]) atomicAdd(&bcnt[i], cnt[i]);
}

// ---------------- Pass 2: scan bucket counts (1 block) ----------------
__global__ __launch_bounds__(512) void bucket_scan_kernel(
    const int* __restrict__ bcnt, int* __restrict__ boff, int* __restrict__ bcur,
    int NB, int E)
{
    __shared__ int s[512];
    int v = (threadIdx.x < (unsigned)NB) ? bcnt[threadIdx.x] : 0;
    s[threadIdx.x] = v;
    __syncthreads();
    for (int off = 1; off < 512; off <<= 1) {
        int t = (threadIdx.x >= (unsigned)off) ? s[threadIdx.x - off] : 0;
        __syncthreads();
        s[threadIdx.x] += t;
        __syncthreads();
    }
    if (threadIdx.x < (unsigned)NB) {
        int ex = s[threadIdx.x] - v;      // exclusive
        boff[threadIdx.x] = ex;
        bcur[threadIdx.x] = ex;
    }
    if (threadIdx.x == 0) boff[NB] = E;
}

// ---------------- Pass 3: partition edges into buckets ----------------
// Output word: src | (local_dst << 20)   (src < 2^20, local_dst < 256)
__global__ __launch_bounds__(256) void partition_kernel(
    const int* __restrict__ src, const int* __restrict__ dst,
    int* __restrict__ bcur, int* __restrict__ pedge, int E)
{
    __shared__ int cnt[MAXB];
    __shared__ int sa[MAXB], sb[MAXB];
    __shared__ int gb[MAXB];      // gbase - local_exclusive_offset
    __shared__ int lcur[MAXB];
    __shared__ int stage[CHUNK];
    __shared__ int tgt[CHUNK];

    for (int i = threadIdx.x; i < MAXB; i += 256) cnt[i] = 0;
    __syncthreads();

    int base = blockIdx.x * CHUNK;
    int vals[16];
    int bs[16];
#pragma unroll
    for (int i = 0; i < 16; i++) {
        int e = base + threadIdx.x + i * 256;
        bs[i] = -1;
        if (e < E) {
            int s_ = src[e];
            int d_ = dst[e];
            int b  = d_ >> BSHIFT;
            bs[i]  = b;
            vals[i] = s_ | ((d_ & (BNODES - 1)) << 20);
            atomicAdd(&cnt[b], 1);
        }
    }
    __syncthreads();

    // exclusive scan of cnt over MAXB entries (ping-pong Hillis-Steele)
    for (int i = threadIdx.x; i < MAXB; i += 256) sa[i] = cnt[i];
    __syncthreads();
    int* cur = sa; int* nxt = sb;
    for (int off = 1; off < MAXB; off <<= 1) {
        for (int i = threadIdx.x; i < MAXB; i += 256)
            nxt[i] = cur[i] + ((i >= off) ? cur[i - off] : 0);
        __syncthreads();
        int* tmp = cur; cur = nxt; nxt = tmp;
    }
    // cur = inclusive scan; reserve global space per bucket
    for (int i = threadIdx.x; i < MAXB; i += 256) {
        int c = cnt[i];
        int lo = cur[i] - c;
        int gbase = c ? atomicAdd(&bcur[i], c) : 0;
        gb[i]   = gbase - lo;
        lcur[i] = lo;
    }
    __syncthreads();

    // stage edges ordered by bucket
#pragma unroll
    for (int i = 0; i < 16; i++) {
        if (bs[i] >= 0) {
            int pos = atomicAdd(&lcur[bs[i]], 1);
            stage[pos] = vals[i];
            tgt[pos]   = gb[bs[i]];
        }
    }
    __syncthreads();

    // coalesced flush: element at stage[idx] goes to pedge[tgt[idx] + idx]
    int cn = min(CHUNK, E - base);
    for (int i = threadIdx.x; i < cn; i += 256)
        pedge[tgt[i] + i] = stage[i];
}

// ---------------- Aggregation: block per bucket, LDS accumulators ----------------
__global__ __launch_bounds__(256) void aggregate_kernel(
    const float* __restrict__ x, const int* __restrict__ pedge,
    const int* __restrict__ boff, float* __restrict__ mean, int N)
{
    __shared__ float acc[BNODES * FEAT];   // 64 KB
    __shared__ int degl[BNODES];
    int b = blockIdx.x;

    for (int i = threadIdx.x * 4; i < BNODES * FEAT; i += 256 * 4)
        *(float4*)&acc[i] = make_float4(0.f, 0.f, 0.f, 0.f);
    for (int i = threadIdx.x; i < BNODES; i += 256) degl[i] = 0;
    __syncthreads();

    int beg = boff[b], end = boff[b + 1];
    int w    = __builtin_amdgcn_readfirstlane(threadIdx.x >> 6);
    int lane = threadIdx.x & 63;

    int e = beg + w * 8;
    // full groups of 8 (4 waves x 8 = stride 32): 8 independent loads in flight
    for (; e + 8 <= end; e += 32) {
        int p0 = pedge[e+0], p1 = pedge[e+1], p2 = pedge[e+2], p3 = pedge[e+3];
        int p4 = pedge[e+4], p5 = pedge[e+5], p6 = pedge[e+6], p7 = pedge[e+7];
        float v0 = x[(size_t)(p0 & 0xFFFFF) * FEAT + lane];
        float v1 = x[(size_t)(p1 & 0xFFFFF) * FEAT + lane];
        float v2 = x[(size_t)(p2 & 0xFFFFF) * FEAT + lane];
        float v3 = x[(size_t)(p3 & 0xFFFFF) * FEAT + lane];
        float v4 = x[(size_t)(p4 & 0xFFFFF) * FEAT + lane];
        float v5 = x[(size_t)(p5 & 0xFFFFF) * FEAT + lane];
        float v6 = x[(size_t)(p6 & 0xFFFFF) * FEAT + lane];
        float v7 = x[(size_t)(p7 & 0xFFFFF) * FEAT + lane];
        atomicAdd(&acc[(p0 >> 20) * FEAT + lane], v0);
        atomicAdd(&acc[(p1 >> 20) * FEAT + lane], v1);
        atomicAdd(&acc[(p2 >> 20) * FEAT + lane], v2);
        atomicAdd(&acc[(p3 >> 20) * FEAT + lane], v3);
        atomicAdd(&acc[(p4 >> 20) * FEAT + lane], v4);
        atomicAdd(&acc[(p5 >> 20) * FEAT + lane], v5);
        atomicAdd(&acc[(p6 >> 20) * FEAT + lane], v6);
        atomicAdd(&acc[(p7 >> 20) * FEAT + lane], v7);
        if (lane == 0) {
            atomicAdd(&degl[p0 >> 20], 1); atomicAdd(&degl[p1 >> 20], 1);
            atomicAdd(&degl[p2 >> 20], 1); atomicAdd(&degl[p3 >> 20], 1);
            atomicAdd(&degl[p4 >> 20], 1); atomicAdd(&degl[p5 >> 20], 1);
            atomicAdd(&degl[p6 >> 20], 1); atomicAdd(&degl[p7 >> 20], 1);
        }
    }
    // tail
    for (int i = 0; i < 8; i++) {
        int ee = e + i;
        if (ee < end) {
            int p = pedge[ee];
            float v = x[(size_t)(p & 0xFFFFF) * FEAT + lane];
            atomicAdd(&acc[(p >> 20) * FEAT + lane], v);
            if (lane == 0) atomicAdd(&degl[p >> 20], 1);
        }
    }
    __syncthreads();

    int nodebase = b << BSHIFT;
    for (int ln = w; ln < BNODES; ln += 4) {
        int node = nodebase + ln;
        if (node < N) {
            float inv = 1.0f / fmaxf((float)degl[ln], 1.0f);
            mean[(size_t)node * FEAT + lane] = acc[ln * FEAT + lane] * inv;
        }
    }
}

// ---------------- Node transforms (lane-per-node, scalar weight loads) ----------------
__global__ __launch_bounds__(256) void sage_kernel(
    float* mean, const float* __restrict__ xin,
    const float* __restrict__ w_l, const float* __restrict__ b_l,
    const float* __restrict__ w_r, int n)
{
    int i = blockIdx.x * blockDim.x + threadIdx.x;
    if (i >= n) return;
    float m[FEAT], xr[FEAT];
    const float4* mv = (const float4*)(mean + (size_t)i * FEAT);
    const float4* xv = (const float4*)(xin + (size_t)i * FEAT);
#pragma unroll
    for (int q = 0; q < FEAT / 4; q++) {
        float4 a = mv[q];
        m[4*q+0] = a.x; m[4*q+1] = a.y; m[4*q+2] = a.z; m[4*q+3] = a.w;
        float4 b = xv[q];
        xr[4*q+0] = b.x; xr[4*q+1] = b.y; xr[4*q+2] = b.z; xr[4*q+3] = b.w;
    }
    float* o = mean + (size_t)i * FEAT;
    for (int j0 = 0; j0 < FEAT; j0 += 4) {
        int j = __builtin_amdgcn_readfirstlane(j0);
        float a0 = b_l[j+0], a1 = b_l[j+1], a2 = b_l[j+2], a3 = b_l[j+3];
#pragma unroll
        for (int k = 0; k < FEAT; k++) {
            float mk = m[k], xk = xr[k];
            const float* wl = w_l + k * FEAT + j;
            const float* wr = w_r + k * FEAT + j;
            a0 += mk * wl[0]; a1 += mk * wl[1]; a2 += mk * wl[2]; a3 += mk * wl[3];
            a0 += xk * wr[0]; a1 += xk * wr[1]; a2 += xk * wr[2]; a3 += xk * wr[3];
        }
        *(float4*)(o + j) = make_float4(fmaxf(a0, 0.f), fmaxf(a1, 0.f),
                                        fmaxf(a2, 0.f), fmaxf(a3, 0.f));
    }
}

__global__ __launch_bounds__(256) void lin_kernel(
    const float* __restrict__ xin, const float* __restrict__ w,
    const float* __restrict__ b, float* __restrict__ out, int n, int do_relu)
{
    int i = blockIdx.x * blockDim.x + threadIdx.x;
    if (i >= n) return;
    float xr[FEAT];
    const float4* xv = (const float4*)(xin + (size_t)i * FEAT);
#pragma unroll
    for (int q = 0; q < FEAT / 4; q++) {
        float4 a = xv[q];
        xr[4*q+0] = a.x; xr[4*q+1] = a.y; xr[4*q+2] = a.z; xr[4*q+3] = a.w;
    }
    float* o = out + (size_t)i * FEAT;
    for (int j0 = 0; j0 < FEAT; j0 += 4) {
        int j = __builtin_amdgcn_readfirstlane(j0);
        float a0 = b[j+0], a1 = b[j+1], a2 = b[j+2], a3 = b[j+3];
#pragma unroll
        for (int k = 0; k < FEAT; k++) {
            float xk = xr[k];
            const float* wp = w + k * FEAT + j;
            a0 += xk * wp[0]; a1 += xk * wp[1]; a2 += xk * wp[2]; a3 += xk * wp[3];
        }
        float4 st;
        if (do_relu)
            st = make_float4(fmaxf(a0, 0.f), fmaxf(a1, 0.f),
                             fmaxf(a2, 0.f), fmaxf(a3, 0.f));
        else
            st = make_float4(a0, a1, a2, a3);
        *(float4*)(o + j) = st;
    }
}

extern "C" void kernel_launch(void* const* d_in, const int* in_sizes, int n_in,
                              void* d_out, int out_size, void* d_ws, size_t ws_size,
                              hipStream_t stream) {
    const float* h      = (const float*)d_in[0];
    const int*   ei     = (const int*)d_in[1];
    const float* w1_l   = (const float*)d_in[2];
    const float* b1_l   = (const float*)d_in[3];
    const float* w1_r   = (const float*)d_in[4];
    const float* w_lin1 = (const float*)d_in[5];
    const float* b_lin1 = (const float*)d_in[6];
    const float* w2_l   = (const float*)d_in[7];
    const float* b2_l   = (const float*)d_in[8];
    const float* w2_r   = (const float*)d_in[9];
    const float* w_lin2 = (const float*)d_in[10];
    const float* b_lin2 = (const float*)d_in[11];

    const int N = in_sizes[0] / FEAT;
    const int E = in_sizes[1] / 2;
    const int* src  = ei;
    const int* dst_ = ei + E;

    const int NB = (N + BNODES - 1) >> BSHIFT;   // 391 for N=100000 (<= 512)
    const int PB = (E + CHUNK - 1) / CHUNK;      // 391 for E=1.6M
    const int nblk = (N + 255) / 256;

    // Workspace: bcnt[512] | boff[513] | bcur[512] | pad | pedge[E] | mean[N*64] | x2[N*64]
    int*   bcnt  = (int*)d_ws;
    int*   boff  = bcnt + MAXB;
    int*   bcur  = boff + (MAXB + 1);
    int*   pedge = bcur + MAXB + 3;              // keep 16B alignment
    float* mean  = (float*)(pedge + E);
    float* x2    = mean + (size_t)N * FEAT;

    // ---- edge partition (once, reused by both conv layers) ----
    hipMemsetAsync(bcnt, 0, MAXB * sizeof(int), stream);
    bucket_count_kernel<<<PB, 256, 0, stream>>>(dst_, bcnt, E);
    bucket_scan_kernel<<<1, 512, 0, stream>>>(bcnt, boff, bcur, NB, E);
    partition_kernel<<<PB, 256, 0, stream>>>(src, dst_, bcur, pedge, E);

    // ---- Layer 1 ----
    aggregate_kernel<<<NB, 256, 0, stream>>>(h, pedge, boff, mean, N);
    sage_kernel<<<nblk, 256, 0, stream>>>(mean, h, w1_l, b1_l, w1_r, N);
    lin_kernel<<<nblk, 256, 0, stream>>>(mean, w_lin1, b_lin1, x2, N, 1);

    // ---- Layer 2 ----
    aggregate_kernel<<<NB, 256, 0, stream>>>(x2, pedge, boff, mean, N);
    sage_kernel<<<nblk, 256, 0, stream>>>(mean, x2, w2_l, b2_l, w2_r, N);
    lin_kernel<<<nblk, 256, 0, stream>>>(mean, w_lin2, b_lin2, (float*)d_out, N, 0);
}

// Round 4
// 503.942 us; speedup vs baseline: 3.6931x; 3.6931x over previous
//
#include <hip/hip_runtime.h>

#define FEAT   64
#define BSHIFT 8                 // 256 dst-nodes per bucket
#define BNODES 256
#define MAXB   512               // supports N <= 131072
#define CHUNK  4096              // edges per partition block

// ---------------- Pass 1: per-bucket edge counts ----------------
__global__ __launch_bounds__(256) void bucket_count_kernel(
    const int* __restrict__ dst, int* __restrict__ bcnt, int E)
{
    __shared__ int cnt[MAXB];
    for (int i = threadIdx.x; i < MAXB; i += 256) cnt[i] = 0;
    __syncthreads();
    int base = blockIdx.x * CHUNK;
    for (int i = threadIdx.x; i < CHUNK; i += 256) {
        int e = base + i;
        if (e < E) atomicAdd(&cnt[dst[e] >> BSHIFT], 1);
    }
    __syncthreads();
    for (int i = threadIdx.x; i < MAXB; i += 256)
        if (cnt[i]) atomicAdd(&bcnt[i], cnt[i]);
}

// ---------------- Pass 2: scan bucket counts (1 block) ----------------
__global__ __launch_bounds__(512) void bucket_scan_kernel(
    const int* __restrict__ bcnt, int* __restrict__ boff, int* __restrict__ bcur,
    int NB, int E)
{
    __shared__ int s[512];
    int v = (threadIdx.x < (unsigned)NB) ? bcnt[threadIdx.x] : 0;
    s[threadIdx.x] = v;
    __syncthreads();
    for (int off = 1; off < 512; off <<= 1) {
        int t = (threadIdx.x >= (unsigned)off) ? s[threadIdx.x - off] : 0;
        __syncthreads();
        s[threadIdx.x] += t;
        __syncthreads();
    }
    if (threadIdx.x < (unsigned)NB) {
        int ex = s[threadIdx.x] - v;      // exclusive
        boff[threadIdx.x] = ex;
        bcur[threadIdx.x] = ex;
    }
    if (threadIdx.x == 0) boff[NB] = E;
}

// ---------------- Pass 3: partition edges into buckets (coalesced staged flush) ----------------
// Output word: src | (local_dst << 20)   (src < 2^20, local_dst < 256)
__global__ __launch_bounds__(256) void partition_kernel(
    const int* __restrict__ src, const int* __restrict__ dst,
    int* __restrict__ bcur, int* __restrict__ pedge, int E)
{
    __shared__ int cnt[MAXB];
    __shared__ int sa[MAXB], sb[MAXB];
    __shared__ int gb[MAXB];      // gbase - local_exclusive_offset
    __shared__ int lcur[MAXB];
    __shared__ int stage[CHUNK];
    __shared__ int tgt[CHUNK];

    for (int i = threadIdx.x; i < MAXB; i += 256) cnt[i] = 0;
    __syncthreads();

    int base = blockIdx.x * CHUNK;
    int vals[16];
    int bs[16];
#pragma unroll
    for (int i = 0; i < 16; i++) {
        int e = base + threadIdx.x + i * 256;
        bs[i] = -1;
        if (e < E) {
            int s_ = src[e];
            int d_ = dst[e];
            int b  = d_ >> BSHIFT;
            bs[i]  = b;
            vals[i] = s_ | ((d_ & (BNODES - 1)) << 20);
            atomicAdd(&cnt[b], 1);
        }
    }
    __syncthreads();

    // exclusive scan of cnt over MAXB entries (ping-pong Hillis-Steele)
    for (int i = threadIdx.x; i < MAXB; i += 256) sa[i] = cnt[i];
    __syncthreads();
    int* cur = sa; int* nxt = sb;
    for (int off = 1; off < MAXB; off <<= 1) {
        for (int i = threadIdx.x; i < MAXB; i += 256)
            nxt[i] = cur[i] + ((i >= off) ? cur[i - off] : 0);
        __syncthreads();
        int* tmp = cur; cur = nxt; nxt = tmp;
    }
    // cur = inclusive scan; reserve global space per bucket
    for (int i = threadIdx.x; i < MAXB; i += 256) {
        int c = cnt[i];
        int lo = cur[i] - c;
        int gbase = c ? atomicAdd(&bcur[i], c) : 0;
        gb[i]   = gbase - lo;
        lcur[i] = lo;
    }
    __syncthreads();

    // stage edges ordered by bucket
#pragma unroll
    for (int i = 0; i < 16; i++) {
        if (bs[i] >= 0) {
            int pos = atomicAdd(&lcur[bs[i]], 1);
            stage[pos] = vals[i];
            tgt[pos]   = gb[bs[i]];
        }
    }
    __syncthreads();

    // coalesced flush: element at stage[idx] goes to pedge[tgt[idx] + idx]
    int cn = min(CHUNK, E - base);
    for (int i = threadIdx.x; i < cn; i += 256)
        pedge[tgt[i] + i] = stage[i];
}

// ---------------- Pass 4: per-bucket CSR build ----------------
// rowptr[node] = boff[b] + local exclusive scan of in-bucket degrees;
// csr_src writes confined to the bucket's private ~16 KB window.
__global__ __launch_bounds__(256) void buildcsr_kernel(
    const int* __restrict__ pedge, const int* __restrict__ boff,
    int* __restrict__ rowptr, int* __restrict__ csr_src, int N, int NB)
{
    __shared__ int hist[BNODES];
    __shared__ int scn[BNODES];
    __shared__ int lcur[BNODES];
    int b = blockIdx.x;
    int beg = boff[b], end = boff[b + 1];

    hist[threadIdx.x] = 0;
    __syncthreads();
    for (int e = beg + (int)threadIdx.x; e < end; e += 256)
        atomicAdd(&hist[pedge[e] >> 20], 1);     // 1 int LDS atomic per edge
    __syncthreads();

    // exclusive scan over 256 bins
    int v = hist[threadIdx.x];
    scn[threadIdx.x] = v;
    __syncthreads();
    for (int off = 1; off < 256; off <<= 1) {
        int t = (threadIdx.x >= (unsigned)off) ? scn[threadIdx.x - off] : 0;
        __syncthreads();
        scn[threadIdx.x] += t;
        __syncthreads();
    }
    int excl = scn[threadIdx.x] - v;

    int node = (b << BSHIFT) + threadIdx.x;
    if (node < N) rowptr[node] = beg + excl;     // coalesced
    if (b == NB - 1 && threadIdx.x == 0) rowptr[N] = boff[NB];  // = E
    lcur[threadIdx.x] = excl;
    __syncthreads();

    // scatter: second read of pedge is L2-hot (16 KB region)
    for (int e = beg + (int)threadIdx.x; e < end; e += 256) {
        int p  = pedge[e];
        int ld = p >> 20;
        int pos = atomicAdd(&lcur[ld], 1);
        csr_src[beg + pos] = p & 0xFFFFF;
    }
}

// ---------------- Aggregation: gather-mean, wave per node ----------------
__global__ __launch_bounds__(256) void gather_kernel(
    const float* __restrict__ x, const int* __restrict__ rowptr,
    const int* __restrict__ csr_src, float* __restrict__ mean, int N)
{
    int node = blockIdx.x * 4 + (threadIdx.x >> 6);
    node = __builtin_amdgcn_readfirstlane(node);   // wave-uniform -> scalar control
    if (node >= N) return;
    int lane = threadIdx.x & 63;
    int beg = rowptr[node], end = rowptr[node + 1];
    float acc = 0.0f;
    int e = beg;
    for (; e + 1 < end; e += 2) {
        int s0 = csr_src[e], s1 = csr_src[e + 1];
        float v0 = x[(size_t)s0 * FEAT + lane];
        float v1 = x[(size_t)s1 * FEAT + lane];
        acc += v0; acc += v1;
    }
    if (e < end) acc += x[(size_t)csr_src[e] * FEAT + lane];
    float inv = 1.0f / fmaxf((float)(end - beg), 1.0f);
    mean[(size_t)node * FEAT + lane] = acc * inv;
}

// ---------------- Node transforms (lane-per-node, scalar weight loads) ----------------
__global__ __launch_bounds__(256) void sage_kernel(
    float* mean, const float* __restrict__ xin,
    const float* __restrict__ w_l, const float* __restrict__ b_l,
    const float* __restrict__ w_r, int n)
{
    int i = blockIdx.x * blockDim.x + threadIdx.x;
    if (i >= n) return;
    float m[FEAT], xr[FEAT];
    const float4* mv = (const float4*)(mean + (size_t)i * FEAT);
    const float4* xv = (const float4*)(xin + (size_t)i * FEAT);
#pragma unroll
    for (int q = 0; q < FEAT / 4; q++) {
        float4 a = mv[q];
        m[4*q+0] = a.x; m[4*q+1] = a.y; m[4*q+2] = a.z; m[4*q+3] = a.w;
        float4 b = xv[q];
        xr[4*q+0] = b.x; xr[4*q+1] = b.y; xr[4*q+2] = b.z; xr[4*q+3] = b.w;
    }
    float* o = mean + (size_t)i * FEAT;
    for (int j0 = 0; j0 < FEAT; j0 += 4) {
        int j = __builtin_amdgcn_readfirstlane(j0);
        float a0 = b_l[j+0], a1 = b_l[j+1], a2 = b_l[j+2], a3 = b_l[j+3];
#pragma unroll
        for (int k = 0; k < FEAT; k++) {
            float mk = m[k], xk = xr[k];
            const float* wl = w_l + k * FEAT + j;
            const float* wr = w_r + k * FEAT + j;
            a0 += mk * wl[0]; a1 += mk * wl[1]; a2 += mk * wl[2]; a3 += mk * wl[3];
            a0 += xk * wr[0]; a1 += xk * wr[1]; a2 += xk * wr[2]; a3 += xk * wr[3];
        }
        *(float4*)(o + j) = make_float4(fmaxf(a0, 0.f), fmaxf(a1, 0.f),
                                        fmaxf(a2, 0.f), fmaxf(a3, 0.f));
    }
}

__global__ __launch_bounds__(256) void lin_kernel(
    const float* __restrict__ xin, const float* __restrict__ w,
    const float* __restrict__ b, float* __restrict__ out, int n, int do_relu)
{
    int i = blockIdx.x * blockDim.x + threadIdx.x;
    if (i >= n) return;
    float xr[FEAT];
    const float4* xv = (const float4*)(xin + (size_t)i * FEAT);
#pragma unroll
    for (int q = 0; q < FEAT / 4; q++) {
        float4 a = xv[q];
        xr[4*q+0] = a.x; xr[4*q+1] = a.y; xr[4*q+2] = a.z; xr[4*q+3] = a.w;
    }
    float* o = out + (size_t)i * FEAT;
    for (int j0 = 0; j0 < FEAT; j0 += 4) {
        int j = __builtin_amdgcn_readfirstlane(j0);
        float a0 = b[j+0], a1 = b[j+1], a2 = b[j+2], a3 = b[j+3];
#pragma unroll
        for (int k = 0; k < FEAT; k++) {
            float xk = xr[k];
            const float* wp = w + k * FEAT + j;
            a0 += xk * wp[0]; a1 += xk * wp[1]; a2 += xk * wp[2]; a3 += xk * wp[3];
        }
        float4 st;
        if (do_relu)
            st = make_float4(fmaxf(a0, 0.f), fmaxf(a1, 0.f),
                             fmaxf(a2, 0.f), fmaxf(a3, 0.f));
        else
            st = make_float4(a0, a1, a2, a3);
        *(float4*)(o + j) = st;
    }
}

extern "C" void kernel_launch(void* const* d_in, const int* in_sizes, int n_in,
                              void* d_out, int out_size, void* d_ws, size_t ws_size,
                              hipStream_t stream) {
    const float* h      = (const float*)d_in[0];
    const int*   ei     = (const int*)d_in[1];
    const float* w1_l   = (const float*)d_in[2];
    const float* b1_l   = (const float*)d_in[3];
    const float* w1_r   = (const float*)d_in[4];
    const float* w_lin1 = (const float*)d_in[5];
    const float* b_lin1 = (const float*)d_in[6];
    const float* w2_l   = (const float*)d_in[7];
    const float* b2_l   = (const float*)d_in[8];
    const float* w2_r   = (const float*)d_in[9];
    const float* w_lin2 = (const float*)d_in[10];
    const float* b_lin2 = (const float*)d_in[11];

    const int N = in_sizes[0] / FEAT;
    const int E = in_sizes[1] / 2;
    const int* src  = ei;
    const int* dst_ = ei + E;

    const int NB = (N + BNODES - 1) >> BSHIFT;   // 391 for N=100000 (<= 512)
    const int PB = (E + CHUNK - 1) / CHUNK;
    const int nblk = (N + 255) / 256;
    const int gblk = (N + 3) / 4;

    // Workspace (ints first), pedge ALIASED onto mean (dead after buildcsr):
    // bcnt[512] | boff[513] | bcur[512] | pad | rowptr[N+1] | pad | csr_src[E] | x2[N*64] | mean[N*64]
    size_t off = 0;
    int* bcnt   = (int*)d_ws + off; off += MAXB;
    int* boff   = (int*)d_ws + off; off += MAXB + 1;
    int* bcur   = (int*)d_ws + off; off += MAXB;
    off = (off + 3) & ~(size_t)3;
    int* rowptr = (int*)d_ws + off; off += (size_t)N + 1;
    off = (off + 3) & ~(size_t)3;
    int* csr    = (int*)d_ws + off; off += (size_t)E;
    off = (off + 3) & ~(size_t)3;
    float* x2   = (float*)d_ws + off; off += (size_t)N * FEAT;
    float* mean = (float*)d_ws + off;
    int* pedge  = (int*)mean;                    // alias: dead once buildcsr completes

    // ---- edge preprocessing (once, reused by both conv layers) ----
    hipMemsetAsync(bcnt, 0, MAXB * sizeof(int), stream);
    bucket_count_kernel<<<PB, 256, 0, stream>>>(dst_, bcnt, E);
    bucket_scan_kernel<<<1, 512, 0, stream>>>(bcnt, boff, bcur, NB, E);
    partition_kernel<<<PB, 256, 0, stream>>>(src, dst_, bcur, pedge, E);
    buildcsr_kernel<<<NB, 256, 0, stream>>>(pedge, boff, rowptr, csr, N, NB);

    // ---- Layer 1 ----
    gather_kernel<<<gblk, 256, 0, stream>>>(h, rowptr, csr, mean, N);
    sage_kernel<<<nblk, 256, 0, stream>>>(mean, h, w1_l, b1_l, w1_r, N);
    lin_kernel<<<nblk, 256, 0, stream>>>(mean, w_lin1, b_lin1, x2, N, 1);

    // ---- Layer 2 ----
    gather_kernel<<<gblk, 256, 0, stream>>>(x2, rowptr, csr, mean, N);
    sage_kernel<<<nblk, 256, 0, stream>>>(mean, x2, w2_l, b2_l, w2_r, N);
    lin_kernel<<<nblk, 256, 0, stream>>>(mean, w_lin2, b_lin2, (float*)d_out, N, 0);
}

// Round 5
// 405.267 us; speedup vs baseline: 4.5923x; 1.2435x over previous
//
#include <hip/hip_runtime.h>

#define FEAT   64
#define BSHIFT 8                 // 256 dst-nodes per bucket
#define BNODES 256
#define MAXB   512               // supports N <= 131072
#define CHUNK  4096              // edges per partition block
#define TNODES 64                // nodes per node-transform block

// ---------------- Pass 1: per-bucket edge counts ----------------
__global__ __launch_bounds__(256) void bucket_count_kernel(
    const int* __restrict__ dst, int* __restrict__ bcnt, int E)
{
    __shared__ int cnt[MAXB];
    for (int i = threadIdx.x; i < MAXB; i += 256) cnt[i] = 0;
    __syncthreads();
    int base = blockIdx.x * CHUNK;
    for (int i = threadIdx.x; i < CHUNK; i += 256) {
        int e = base + i;
        if (e < E) atomicAdd(&cnt[dst[e] >> BSHIFT], 1);
    }
    __syncthreads();
    for (int i = threadIdx.x; i < MAXB; i += 256)
        if (cnt[i]) atomicAdd(&bcnt[i], cnt[i]);
}

// ---------------- Pass 2: scan bucket counts (1 block) ----------------
__global__ __launch_bounds__(512) void bucket_scan_kernel(
    const int* __restrict__ bcnt, int* __restrict__ boff, int* __restrict__ bcur,
    int NB, int E)
{
    __shared__ int s[512];
    int v = (threadIdx.x < (unsigned)NB) ? bcnt[threadIdx.x] : 0;
    s[threadIdx.x] = v;
    __syncthreads();
    for (int off = 1; off < 512; off <<= 1) {
        int t = (threadIdx.x >= (unsigned)off) ? s[threadIdx.x - off] : 0;
        __syncthreads();
        s[threadIdx.x] += t;
        __syncthreads();
    }
    if (threadIdx.x < (unsigned)NB) {
        int ex = s[threadIdx.x] - v;      // exclusive
        boff[threadIdx.x] = ex;
        bcur[threadIdx.x] = ex;
    }
    if (threadIdx.x == 0) boff[NB] = E;
}

// ---------------- Pass 3: partition edges into buckets (coalesced staged flush) ----------------
// Output word: src | (local_dst << 20)
__global__ __launch_bounds__(256) void partition_kernel(
    const int* __restrict__ src, const int* __restrict__ dst,
    int* __restrict__ bcur, int* __restrict__ pedge, int E)
{
    __shared__ int cnt[MAXB];
    __shared__ int sa[MAXB], sb[MAXB];
    __shared__ int gb[MAXB];
    __shared__ int lcur[MAXB];
    __shared__ int stage[CHUNK];
    __shared__ int tgt[CHUNK];

    for (int i = threadIdx.x; i < MAXB; i += 256) cnt[i] = 0;
    __syncthreads();

    int base = blockIdx.x * CHUNK;
    int vals[16];
    int bs[16];
#pragma unroll
    for (int i = 0; i < 16; i++) {
        int e = base + threadIdx.x + i * 256;
        bs[i] = -1;
        if (e < E) {
            int s_ = src[e];
            int d_ = dst[e];
            int b  = d_ >> BSHIFT;
            bs[i]  = b;
            vals[i] = s_ | ((d_ & (BNODES - 1)) << 20);
            atomicAdd(&cnt[b], 1);
        }
    }
    __syncthreads();

    for (int i = threadIdx.x; i < MAXB; i += 256) sa[i] = cnt[i];
    __syncthreads();
    int* cur = sa; int* nxt = sb;
    for (int off = 1; off < MAXB; off <<= 1) {
        for (int i = threadIdx.x; i < MAXB; i += 256)
            nxt[i] = cur[i] + ((i >= off) ? cur[i - off] : 0);
        __syncthreads();
        int* tmp = cur; cur = nxt; nxt = tmp;
    }
    for (int i = threadIdx.x; i < MAXB; i += 256) {
        int c = cnt[i];
        int lo = cur[i] - c;
        int gbase = c ? atomicAdd(&bcur[i], c) : 0;
        gb[i]   = gbase - lo;
        lcur[i] = lo;
    }
    __syncthreads();

#pragma unroll
    for (int i = 0; i < 16; i++) {
        if (bs[i] >= 0) {
            int pos = atomicAdd(&lcur[bs[i]], 1);
            stage[pos] = vals[i];
            tgt[pos]   = gb[bs[i]];
        }
    }
    __syncthreads();

    int cn = min(CHUNK, E - base);
    for (int i = threadIdx.x; i < cn; i += 256)
        pedge[tgt[i] + i] = stage[i];
}

// ---------------- Pass 4: per-bucket CSR build ----------------
__global__ __launch_bounds__(256) void buildcsr_kernel(
    const int* __restrict__ pedge, const int* __restrict__ boff,
    int* __restrict__ rowptr, int* __restrict__ csr_src, int N, int NB)
{
    __shared__ int hist[BNODES];
    __shared__ int scn[BNODES];
    __shared__ int lcur[BNODES];
    int b = blockIdx.x;
    int beg = boff[b], end = boff[b + 1];

    hist[threadIdx.x] = 0;
    __syncthreads();
    for (int e = beg + (int)threadIdx.x; e < end; e += 256)
        atomicAdd(&hist[pedge[e] >> 20], 1);
    __syncthreads();

    int v = hist[threadIdx.x];
    scn[threadIdx.x] = v;
    __syncthreads();
    for (int off = 1; off < 256; off <<= 1) {
        int t = (threadIdx.x >= (unsigned)off) ? scn[threadIdx.x - off] : 0;
        __syncthreads();
        scn[threadIdx.x] += t;
        __syncthreads();
    }
    int excl = scn[threadIdx.x] - v;

    int node = (b << BSHIFT) + threadIdx.x;
    if (node < N) rowptr[node] = beg + excl;
    if (b == NB - 1 && threadIdx.x == 0) rowptr[N] = boff[NB];
    lcur[threadIdx.x] = excl;
    __syncthreads();

    for (int e = beg + (int)threadIdx.x; e < end; e += 256) {
        int p  = pedge[e];
        int ld = p >> 20;
        int pos = atomicAdd(&lcur[ld], 1);
        csr_src[beg + pos] = p & 0xFFFFF;
    }
}

// ---------------- Aggregation: gather-mean ----------------
// Wave per node; lanes = 4 edge-groups x 16 float4-slots. 4x fewer load
// instructions than lane-per-float; xor-shuffle reduce; 256B coalesced store.
__global__ __launch_bounds__(256) void gather_kernel(
    const float* __restrict__ x, const int* __restrict__ rowptr,
    const int* __restrict__ csr_src, float* __restrict__ mean, int N)
{
    int node = blockIdx.x * 4 + (threadIdx.x >> 6);
    if (node >= N) return;
    int lane = threadIdx.x & 63;
    int g  = lane >> 4;          // edge group 0..3
    int f4 = lane & 15;          // float4 slot within row
    int beg = rowptr[node], end = rowptr[node + 1];

    float4 acc = make_float4(0.f, 0.f, 0.f, 0.f);
    int e = beg + g;
    for (; e + 4 < end; e += 8) {             // 8 edges in flight per wave iter
        int s0 = csr_src[e];
        int s1 = csr_src[e + 4];
        float4 v0 = ((const float4*)(x + (size_t)s0 * FEAT))[f4];
        float4 v1 = ((const float4*)(x + (size_t)s1 * FEAT))[f4];
        acc.x += v0.x; acc.y += v0.y; acc.z += v0.z; acc.w += v0.w;
        acc.x += v1.x; acc.y += v1.y; acc.z += v1.z; acc.w += v1.w;
    }
    if (e < end) {
        int s0 = csr_src[e];
        float4 v0 = ((const float4*)(x + (size_t)s0 * FEAT))[f4];
        acc.x += v0.x; acc.y += v0.y; acc.z += v0.z; acc.w += v0.w;
    }
    // reduce across the 4 edge groups (lanes differing in bits 4,5)
#pragma unroll
    for (int mask = 16; mask <= 32; mask <<= 1) {
        acc.x += __shfl_xor(acc.x, mask, 64);
        acc.y += __shfl_xor(acc.y, mask, 64);
        acc.z += __shfl_xor(acc.z, mask, 64);
        acc.w += __shfl_xor(acc.w, mask, 64);
    }
    if (g == 0) {
        float inv = 1.0f / fmaxf((float)(end - beg), 1.0f);
        acc.x *= inv; acc.y *= inv; acc.z *= inv; acc.w *= inv;
        ((float4*)(mean + (size_t)node * FEAT))[f4] = acc;   // 16 lanes x 16B = 256B
    }
}

// ---------------- Node transforms ----------------
// Block = 64 nodes; wave w computes output features [16w,16w+16) for all 64
// nodes (lane = node). j wave-uniform -> scalar weight loads. Outputs staged
// in LDS (stride 65: bank = (lane+c)%32, conflict-free) and flushed with
// lane = feature -> full 256B coalesced stores.
__global__ __launch_bounds__(256) void sage_kernel(
    float* mean, const float* __restrict__ xin,
    const float* __restrict__ w_l, const float* __restrict__ b_l,
    const float* __restrict__ w_r, int n)
{
    __shared__ float ostage[TNODES * (FEAT + 1)];
    int wave = threadIdx.x >> 6;
    int lane = threadIdx.x & 63;
    int base = blockIdx.x * TNODES;
    int node = base + lane;
    int node_c = min(node, n - 1);
    int j0 = __builtin_amdgcn_readfirstlane(wave * 16);

    float acc[16];
#pragma unroll
    for (int j = 0; j < 16; j++) acc[j] = b_l[j0 + j];

    const float4* mv = (const float4*)(mean + (size_t)node_c * FEAT);
    const float4* xv = (const float4*)(xin + (size_t)node_c * FEAT);
#pragma unroll
    for (int q = 0; q < FEAT / 4; q++) {
        float4 m4 = mv[q];
        float4 x4 = xv[q];
        float mk[4] = {m4.x, m4.y, m4.z, m4.w};
        float xk[4] = {x4.x, x4.y, x4.z, x4.w};
#pragma unroll
        for (int kk = 0; kk < 4; kk++) {
            int k = q * 4 + kk;
            const float* wl = w_l + k * FEAT + j0;   // uniform -> s_load
            const float* wr = w_r + k * FEAT + j0;
#pragma unroll
            for (int j = 0; j < 16; j++)
                acc[j] += mk[kk] * wl[j] + xk[kk] * wr[j];
        }
    }
#pragma unroll
    for (int j = 0; j < 16; j++)
        ostage[lane * (FEAT + 1) + j0 + j] = fmaxf(acc[j], 0.0f);
    __syncthreads();

#pragma unroll
    for (int r = 0; r < 16; r++) {
        int row = wave * 16 + r;
        int gn = base + row;
        if (gn < n)
            mean[(size_t)gn * FEAT + lane] = ostage[row * (FEAT + 1) + lane];
    }
}

__global__ __launch_bounds__(256) void lin_kernel(
    const float* __restrict__ xin, const float* __restrict__ w,
    const float* __restrict__ b, float* __restrict__ out, int n, int do_relu)
{
    __shared__ float ostage[TNODES * (FEAT + 1)];
    int wave = threadIdx.x >> 6;
    int lane = threadIdx.x & 63;
    int base = blockIdx.x * TNODES;
    int node = base + lane;
    int node_c = min(node, n - 1);
    int j0 = __builtin_amdgcn_readfirstlane(wave * 16);

    float acc[16];
#pragma unroll
    for (int j = 0; j < 16; j++) acc[j] = b[j0 + j];

    const float4* xv = (const float4*)(xin + (size_t)node_c * FEAT);
#pragma unroll
    for (int q = 0; q < FEAT / 4; q++) {
        float4 x4 = xv[q];
        float xk[4] = {x4.x, x4.y, x4.z, x4.w};
#pragma unroll
        for (int kk = 0; kk < 4; kk++) {
            int k = q * 4 + kk;
            const float* wp = w + k * FEAT + j0;     // uniform -> s_load
#pragma unroll
            for (int j = 0; j < 16; j++)
                acc[j] += xk[kk] * wp[j];
        }
    }
#pragma unroll
    for (int j = 0; j < 16; j++) {
        float v = acc[j];
        ostage[lane * (FEAT + 1) + j0 + j] = do_relu ? fmaxf(v, 0.0f) : v;
    }
    __syncthreads();

#pragma unroll
    for (int r = 0; r < 16; r++) {
        int row = wave * 16 + r;
        int gn = base + row;
        if (gn < n)
            out[(size_t)gn * FEAT + lane] = ostage[row * (FEAT + 1) + lane];
    }
}

extern "C" void kernel_launch(void* const* d_in, const int* in_sizes, int n_in,
                              void* d_out, int out_size, void* d_ws, size_t ws_size,
                              hipStream_t stream) {
    const float* h      = (const float*)d_in[0];
    const int*   ei     = (const int*)d_in[1];
    const float* w1_l   = (const float*)d_in[2];
    const float* b1_l   = (const float*)d_in[3];
    const float* w1_r   = (const float*)d_in[4];
    const float* w_lin1 = (const float*)d_in[5];
    const float* b_lin1 = (const float*)d_in[6];
    const float* w2_l   = (const float*)d_in[7];
    const float* b2_l   = (const float*)d_in[8];
    const float* w2_r   = (const float*)d_in[9];
    const float* w_lin2 = (const float*)d_in[10];
    const float* b_lin2 = (const float*)d_in[11];

    const int N = in_sizes[0] / FEAT;
    const int E = in_sizes[1] / 2;
    const int* src  = ei;
    const int* dst_ = ei + E;

    const int NB = (N + BNODES - 1) >> BSHIFT;
    const int PB = (E + CHUNK - 1) / CHUNK;
    const int tblk = (N + TNODES - 1) / TNODES;   // node-transform blocks
    const int gblk = (N + 3) / 4;

    // Workspace: bcnt | boff | bcur | rowptr[N+1] | csr_src[E] | x2[N*64] | mean[N*64]
    // pedge aliased onto mean (dead after buildcsr).
    size_t off = 0;
    int* bcnt   = (int*)d_ws + off; off += MAXB;
    int* boff   = (int*)d_ws + off; off += MAXB + 1;
    int* bcur   = (int*)d_ws + off; off += MAXB;
    off = (off + 3) & ~(size_t)3;
    int* rowptr = (int*)d_ws + off; off += (size_t)N + 1;
    off = (off + 3) & ~(size_t)3;
    int* csr    = (int*)d_ws + off; off += (size_t)E;
    off = (off + 3) & ~(size_t)3;
    float* x2   = (float*)d_ws + off; off += (size_t)N * FEAT;
    float* mean = (float*)d_ws + off;
    int* pedge  = (int*)mean;

    // ---- edge preprocessing (once, reused by both conv layers) ----
    hipMemsetAsync(bcnt, 0, MAXB * sizeof(int), stream);
    bucket_count_kernel<<<PB, 256, 0, stream>>>(dst_, bcnt, E);
    bucket_scan_kernel<<<1, 512, 0, stream>>>(bcnt, boff, bcur, NB, E);
    partition_kernel<<<PB, 256, 0, stream>>>(src, dst_, bcur, pedge, E);
    buildcsr_kernel<<<NB, 256, 0, stream>>>(pedge, boff, rowptr, csr, N, NB);

    // ---- Layer 1 ----
    gather_kernel<<<gblk, 256, 0, stream>>>(h, rowptr, csr, mean, N);
    sage_kernel<<<tblk, 256, 0, stream>>>(mean, h, w1_l, b1_l, w1_r, N);
    lin_kernel<<<tblk, 256, 0, stream>>>(mean, w_lin1, b_lin1, x2, N, 1);

    // ---- Layer 2 ----
    gather_kernel<<<gblk, 256, 0, stream>>>(x2, rowptr, csr, mean, N);
    sage_kernel<<<tblk, 256, 0, stream>>>(mean, x2, w2_l, b2_l, w2_r, N);
    lin_kernel<<<tblk, 256, 0, stream>>>(mean, w_lin2, b_lin2, (float*)d_out, N, 0);
}